// Round 8
// baseline (377.214 us; speedup 1.0000x reference)
//
#include <hip/hip_runtime.h>
#include <hip/hip_bf16.h>
#include <cmath>

#define NSP 119
#define UNITS 512
#define NFEAT 360
#define KP1 384          // NFEAT padded to multiple of 32

typedef __attribute__((ext_vector_type(8))) short short8;
typedef __attribute__((ext_vector_type(4))) float floatx4;

// ---------- constant index tables ----------
__constant__ int T2I[15] = {0,1,1,2,2,2,3,3,3,3,4,4,4,4,4};
__constant__ int T2J[15] = {0,0,1,0,1,2,0,1,2,3,0,1,2,3,4};
__constant__ int T3A[35] = {0, 1,1,1, 2,2,2,2,2,2, 3,3,3,3,3,3,3,3,3,3, 4,4,4,4,4,4,4,4,4,4,4,4,4,4,4};
__constant__ int T3B[35] = {0, 0,1,1, 0,1,1,2,2,2, 0,1,1,2,2,2,3,3,3,3, 0,1,1,2,2,2,3,3,3,3,4,4,4,4,4};
__constant__ int T3C[35] = {0, 0,0,1, 0,0,1,0,1,2, 0,0,1,0,1,2,0,1,2,3, 0,0,1,0,1,2,0,1,2,3,0,1,2,3,4};
__constant__ int P2X[6] = {0,1,1,2,2,2};
__constant__ int P2Y[6] = {0,0,1,0,1,2};
__constant__ int P3X[10] = {0,1,1,1,2,2,2,2,2,2};
__constant__ int P3Y[10] = {0,0,1,1,0,1,1,2,2,2};
__constant__ int P3Z[10] = {0,0,0,1,0,0,1,0,1,2};

// ---------- phase 1a: histogram of in-cutoff pairs per center atom ----------
__global__ __launch_bounds__(256) void hist_kernel(
    const float* __restrict__ R, const int* __restrict__ nbr,
    const float* __restrict__ offsets, int* __restrict__ counts, int npairs)
{
    int p = blockIdx.x * 256 + threadIdx.x;
    if (p >= npairs) return;
    int i = nbr[p];
    int j = nbr[npairs + p];
    float dx = R[3*j]   - R[3*i]   + offsets[3*p];
    float dy = R[3*j+1] - R[3*i+1] + offsets[3*p+1];
    float dz = R[3*j+2] - R[3*i+2] + offsets[3*p+2];
    float dr2 = dx*dx + dy*dy + dz*dz;
    if (dr2 < 36.0f) atomicAdd(&counts[i], 1);
}

// ---------- phase 1b: exclusive scan, single block, 32 items/thread ----------
__global__ __launch_bounds__(1024) void scan_kernel(
    const int* __restrict__ counts, int* __restrict__ offs,
    int* __restrict__ cursor, int n)
{
    int tid = threadIdx.x;
    int lane = tid & 63, wid = tid >> 6;
    int beg = tid * 32;
    int local[32];
    int s = 0;
    #pragma unroll
    for (int k = 0; k < 32; ++k) {
        int idx = beg + k;
        int v = (idx < n) ? counts[idx] : 0;
        local[k] = s;
        s += v;
    }
    int incl = s;
    #pragma unroll
    for (int off = 1; off < 64; off <<= 1) {
        int t = __shfl_up(incl, off, 64);
        if (lane >= off) incl += t;
    }
    __shared__ int wsum[16];
    if (lane == 63) wsum[wid] = incl;
    __syncthreads();
    if (tid < 16) {
        int v = wsum[tid];
        int inc2 = v;
        #pragma unroll
        for (int off = 1; off < 16; off <<= 1) {
            int t = __shfl_up(inc2, off, 64);
            if (tid >= off) inc2 += t;
        }
        wsum[tid] = inc2 - v;
    }
    __syncthreads();
    int base = wsum[wid] + (incl - s);
    #pragma unroll
    for (int k = 0; k < 32; ++k) {
        int idx = beg + k;
        if (idx < n) { int v = base + local[k]; offs[idx] = v; cursor[idx] = v; }
    }
}

// ---------- phase 1c (merged): scatter + per-pair rad[5]+dn[3] record ----------
// One pass over all pairs: in-cutoff pairs claim a slot in their atom's
// segment via cursor atomic, compute the full record, write pairdata[pos].
// (Replaces the former scatter_kernel + pair_compute_kernel two-pass scheme.)
__global__ __launch_bounds__(256) void scatter_pair_kernel(
    const float* __restrict__ R, const int* __restrict__ Z,
    const int* __restrict__ nbr, const float* __restrict__ offsets,
    const float* __restrict__ emb, int* __restrict__ cursor,
    float* __restrict__ pairdata, int npairs)
{
    int p = blockIdx.x * 256 + threadIdx.x;
    if (p >= npairs) return;
    int i = nbr[p], j = nbr[npairs + p];
    float dx = R[3*j]   - R[3*i]   + offsets[3*p];
    float dy = R[3*j+1] - R[3*i+1] + offsets[3*p+1];
    float dz = R[3*j+2] - R[3*i+2] + offsets[3*p+2];
    float dr2 = dx*dx + dy*dy + dz*dz;
    if (!(dr2 < 36.0f)) return;
    int pos = atomicAdd(&cursor[i], 1);

    float dr = sqrtf(dr2);
    float inv = 1.0f / (dr + 1e-5f);
    float cutoff = 0.5f * (cosf(0.523598775598299f * dr) + 1.0f); // pi/R_MAX
    const float betta = 49.0f / 36.0f;
    const float rad_norm = expf(0.75f * logf(2.0f * betta / 3.14159265358979f));
    float basis[7];
    #pragma unroll
    for (int b = 0; b < 7; ++b) {
        float sh = 0.5f + b * (5.5f / 6.0f);
        float d = dr - sh;
        basis[b] = rad_norm * expf(-betta * d * d);
    }
    const float* e = emb + ((size_t)Z[j] * NSP + Z[i]) * 35;
    const float EMBN = 0.377964473009227f; // 1/sqrt(7)
    float rec[8];
    #pragma unroll
    for (int r = 0; r < 5; ++r) {
        float s = 0.f;
        #pragma unroll
        for (int b = 0; b < 7; ++b) s += e[r*7 + b] * basis[b];
        rec[r] = EMBN * s * cutoff;
    }
    rec[5] = dx * inv; rec[6] = dy * inv; rec[7] = dz * inv;
    float4* out = (float4*)(pairdata + (size_t)pos * 8);
    out[0] = make_float4(rec[0], rec[1], rec[2], rec[3]);
    out[1] = make_float4(rec[4], rec[5], rec[6], rec[7]);
}

// ---------- phase 2: one wave per atom: moments + contractions -> 360 bf16 feats ----------
#define SREC 12   // stage record stride (floats); [0..4]=rad, [5..7]=dn, [8]=1.0
__global__ __launch_bounds__(256) void moment_feat_kernel(
    const float* __restrict__ pairdata, const int* __restrict__ offs,
    const int* __restrict__ counts, __hip_bfloat16* __restrict__ feats, int natoms)
{
    int wv = threadIdx.x >> 6, lane = threadIdx.x & 63;
    int a = blockIdx.x * 4 + wv;
    __shared__ float stage[4][64][SREC];
    __shared__ float F[4][200];
    __shared__ float B2[4][135];
    __shared__ float A3[4][75];
    if (a >= natoms) return;   // wave-uniform; no __syncthreads in this kernel

    int start = offs[a], cnt = counts[a];

    int cr0, f00 = 8, f01 = 8, f02 = 8;
    if (lane < 5)       { cr0 = lane; }
    else if (lane < 20) { int c = lane - 5;  cr0 = c / 3; f00 = 5 + c % 3; }
    else if (lane < 50) { int c = lane - 20; cr0 = c / 6; int k = c % 6;
                          f00 = 5 + P2X[k]; f01 = 5 + P2Y[k]; }
    else                { int c = lane - 50; cr0 = c / 10; int k = c % 10;
                          f00 = 5 + P3X[k]; f01 = 5 + P3Y[k]; f02 = 5 + P3Z[k]; }
    int cr1 = 8, f10 = 8, f11 = 8, f12 = 8;
    if (lane < 36) { int c = 14 + lane; cr1 = c / 10; int k = c % 10;
                     f10 = 5 + P3X[k]; f11 = 5 + P3Y[k]; f12 = 5 + P3Z[k]; }

    float acc0 = 0.f, acc1 = 0.f;
    for (int base = 0; base < cnt; base += 64) {
        int m = min(64, cnt - base);
        if (lane < m) {
            const float4* pd = (const float4*)(pairdata + (size_t)(start + base + lane) * 8);
            float4 u = pd[0], v = pd[1];
            float* st = stage[wv][lane];
            ((float4*)st)[0] = u;
            ((float4*)st)[1] = v;
            st[8] = 1.0f;
        }
        __builtin_amdgcn_wave_barrier();
        for (int q = 0; q < m; ++q) {
            const float* s = stage[wv][q];
            acc0 += s[cr0] * s[f00] * s[f01] * s[f02];
            acc1 += s[cr1] * s[f10] * s[f11] * s[f12];
        }
        __builtin_amdgcn_wave_barrier();
    }
    float* raw = &stage[wv][0][0];
    __builtin_amdgcn_wave_barrier();
    raw[lane] = acc0;
    if (lane < 36) raw[64 + lane] = acc1;
    __builtin_amdgcn_wave_barrier();

    #pragma unroll
    for (int it = 0; it < 4; ++it) {
        int idx = lane + it * 64;
        if (idx < 200) {
            float v;
            if (idx < 20) {
                v = raw[idx];
            } else if (idx < 65) {
                int rel = idx - 20, r = rel / 9, q = rel % 9, x = q / 3, y = q % 3;
                int hi = max(x, y), lo = min(x, y);
                v = raw[20 + r*6 + hi*(hi+1)/2 + lo];
            } else {
                int rel = idx - 65, r = rel / 27, q = rel % 27;
                int x = q / 9, y = (q / 3) % 3, z = q % 3;
                int A = max(x, max(y, z)), C = min(x, min(y, z)), B = x + y + z - A - C;
                v = raw[50 + r*10 + A*(A+1)*(A+2)/6 + B*(B+1)/2 + C];
            }
            F[wv][idx] = v;
        }
    }
    __builtin_amdgcn_wave_barrier();

    const float* M0 = F[wv];
    const float* M1 = F[wv] + 5;    // [r*3+x]
    const float* M2 = F[wv] + 20;   // [r*9+x*3+y]
    const float* M3 = F[wv] + 65;   // [r*27+x*9+y*3+z]

    #pragma unroll
    for (int it = 0; it < 4; ++it) {
        int idx = lane + it * 64;
        if (idx < 135) {
            int p = idx / 9, zw = idx % 9, z = zw / 3, w_ = zw % 3;
            int r = T2I[p], s = T2J[p];
            float b = 0.f;
            for (int x = 0; x < 3; ++x)
                for (int y = 0; y < 3; ++y)
                    b += M3[r*27 + x*9 + y*3 + z] * M3[s*27 + x*9 + y*3 + w_];
            B2[wv][idx] = b;
        } else if (idx < 210) {
            int e = idx - 135;
            int rs = e / 3, z = e % 3;
            int r = rs / 5, s = rs % 5;
            float av = 0.f;
            for (int x = 0; x < 3; ++x)
                for (int y = 0; y < 3; ++y)
                    av += M3[r*27 + x*9 + y*3 + z] * M2[s*9 + x*3 + y];
            A3[wv][e] = av;
        }
    }
    __builtin_amdgcn_wave_barrier();

    __hip_bfloat16* out = feats + (size_t)a * KP1;
    for (int f = lane; f < NFEAT; f += 64) {
        float v = 0.f;
        if (f < 5) {
            v = M0[f];
        } else if (f < 20) {                 // c1
            int p = f - 5, r = T2I[p], s = T2J[p];
            for (int x = 0; x < 3; ++x) v += M1[r*3+x] * M1[s*3+x];
        } else if (f < 35) {                 // c2
            int p = f - 20, r = T2I[p], s = T2J[p];
            for (int q = 0; q < 9; ++q) v += M2[r*9+q] * M2[s*9+q];
        } else if (f < 50) {                 // c3
            int p = f - 35, r = T2I[p], s = T2J[p];
            for (int q = 0; q < 27; ++q) v += M3[r*27+q] * M3[s*27+q];
        } else if (f < 85) {                 // c4
            int q = f - 50, r = T3A[q], s = T3B[q], t = T3C[q];
            for (int x = 0; x < 3; ++x)
                for (int y = 0; y < 3; ++y)
                    for (int z = 0; z < 3; ++z)
                        v += M2[r*9+x*3+y] * M2[s*9+x*3+z] * M2[t*9+y*3+z];
        } else if (f < 160) {                // c5
            int q = f - 85, p = q / 5, t = q % 5, r = T2I[p], s = T2J[p];
            for (int x = 0; x < 3; ++x)
                for (int y = 0; y < 3; ++y)
                    v += M1[r*3+x] * M1[s*3+y] * M2[t*9+x*3+y];
        } else if (f < 235) {                // c6 via B2
            int q = f - 160, p = q / 5, t = q % 5;
            for (int zw = 0; zw < 9; ++zw)
                v += B2[wv][p*9 + zw] * M2[t*9 + zw];
        } else {                             // c7 via A3
            int q = f - 235, r = q / 25, s = (q / 5) % 5, t = q % 5;
            for (int z = 0; z < 3; ++z)
                v += A3[wv][(r*5+s)*3 + z] * M1[t*3 + z];
        }
        out[f] = __float2bfloat16(v);
    }
}

// ---------- weight transpose+pad to bf16: Wt[n*Kp+k] = W[k*N+n] ----------
__global__ __launch_bounds__(256) void prep_w_t(
    const float* __restrict__ W, __hip_bfloat16* __restrict__ Wt,
    int K, int N, int Kp)
{
    int idx = blockIdx.x * 256 + threadIdx.x;
    if (idx >= N * Kp) return;
    int n = idx / Kp, k = idx % Kp;
    float v = (k < K) ? W[(size_t)k * N + n] : 0.f;
    Wt[idx] = __float2bfloat16(v);
}

// ---------- bf16 MFMA GEMM, 128x64 tile, BK=32, reg-staged double-buffer ----------
// R5-proven config: 2D grid (row-tile, col-tile). The XCD-swizzled 1D grid
// (R6/R7) caused a 40x HBM WRITE amplification — do not reintroduce it.
// LDS swizzle: chunk (row r, c) at pos r*4 + (c ^ ((r>>1)&3)) -> conflict-free.
// One __syncthreads per K-iter (double LDS buffer); 2-deep register prefetch.
__global__ __launch_bounds__(256) void gemm_mfma_swish(
    const __hip_bfloat16* __restrict__ A, const __hip_bfloat16* __restrict__ Bt,
    const float* __restrict__ bias, __hip_bfloat16* __restrict__ C,
    const float* __restrict__ w3, float* __restrict__ outacc,
    int Kp, int M, float alpha, float a3, int fuse)
{
    __shared__ float4 As[2][512];   // 128 rows x 4 chunks
    __shared__ float4 Bs[2][256];   // 64 rows x 4 chunks
    int tid = threadIdx.x;
    int wave = tid >> 6, lane = tid & 63;
    int quad = lane >> 4, l16 = lane & 15;
    int wm = wave >> 1, wn = wave & 1;   // 2x2 waves: 64-row x 32-col each
    int rowBase = blockIdx.x * 128;
    int colBase = blockIdx.y * 64;

    floatx4 acc[4][2] = {};

    // staging decode: thread -> (row, chunk)
    int rA0 = tid >> 2, cA = tid & 3;   // A rows 0..63
    int rA1 = rA0 + 64;                 // A rows 64..127
    int pA0 = rA0 * 4 + (cA ^ ((rA0 >> 1) & 3));
    int pA1 = rA1 * 4 + (cA ^ ((rA1 >> 1) & 3));
    int pB  = rA0 * 4 + (cA ^ ((rA0 >> 1) & 3));   // B rows 0..63

    const char* pa0 = (const char*)(A  + (size_t)(rowBase + rA0) * Kp + cA * 8);
    const char* pa1 = (const char*)(A  + (size_t)(rowBase + rA1) * Kp + cA * 8);
    const char* pb  = (const char*)(Bt + (size_t)(colBase + rA0) * Kp + cA * 8);

    // fragment read positions
    int posA[4], posB[2];
    #pragma unroll
    for (int t = 0; t < 4; ++t) {
        int rr = wm * 64 + t * 16 + l16;
        posA[t] = rr * 4 + (quad ^ ((rr >> 1) & 3));
    }
    #pragma unroll
    for (int u = 0; u < 2; ++u) {
        int cc = wn * 32 + u * 16 + l16;
        posB[u] = cc * 4 + (quad ^ ((cc >> 1) & 3));
    }

    int nK = Kp >> 5;
    // 2-deep prefetch: slot kt&1 holds data for iteration kt
    float4 ra0[2], ra1[2], rb[2];
    ra0[0] = *(const float4*)pa0;
    ra1[0] = *(const float4*)pa1;
    rb[0]  = *(const float4*)pb;
    ra0[1] = *(const float4*)(pa0 + 64);
    ra1[1] = *(const float4*)(pa1 + 64);
    rb[1]  = *(const float4*)(pb  + 64);

    for (int kt = 0; kt < nK; ++kt) {
        int sl = kt & 1;
        As[sl][pA0] = ra0[sl];
        As[sl][pA1] = ra1[sl];
        Bs[sl][pB]  = rb[sl];
        __syncthreads();
        if (kt + 2 < nK) {
            int off = (kt + 2) << 6;   // 32 bf16 = 64 bytes
            ra0[sl] = *(const float4*)(pa0 + off);
            ra1[sl] = *(const float4*)(pa1 + off);
            rb[sl]  = *(const float4*)(pb  + off);
        }
        short8 af[4], bf[2];
        #pragma unroll
        for (int t = 0; t < 4; ++t) af[t] = *(const short8*)(As[sl] + posA[t]);
        #pragma unroll
        for (int u = 0; u < 2; ++u) bf[u] = *(const short8*)(Bs[sl] + posB[u]);
        #pragma unroll
        for (int t = 0; t < 4; ++t)
            #pragma unroll
            for (int u = 0; u < 2; ++u)
                acc[t][u] = __builtin_amdgcn_mfma_f32_16x16x32_bf16(
                    af[t], bf[u], acc[t][u], 0, 0, 0);
        // next iter writes the other LDS buffer, whose readers all passed
        // this iter's barrier already -> no trailing barrier needed.
    }

    if (!fuse) {
        #pragma unroll
        for (int u = 0; u < 2; ++u) {
            int col = colBase + wn * 32 + u * 16 + l16;
            float bc = 0.1f * bias[col];
            #pragma unroll
            for (int t = 0; t < 4; ++t) {
                int row0 = rowBase + wm * 64 + t * 16 + quad * 4;
                #pragma unroll
                for (int r = 0; r < 4; ++r) {
                    float x2 = alpha * acc[t][u][r] + bc;
                    float v = x2 / (1.f + expf(-x2));
                    C[(size_t)(row0 + r) * UNITS + col] = __float2bfloat16(v);
                }
            }
        }
    } else {
        float rowsum[4][4] = {};
        #pragma unroll
        for (int u = 0; u < 2; ++u) {
            int col = colBase + wn * 32 + u * 16 + l16;
            float bc = 0.1f * bias[col];
            float w3c = w3[col] * a3;
            #pragma unroll
            for (int t = 0; t < 4; ++t)
                #pragma unroll
                for (int r = 0; r < 4; ++r) {
                    float x2 = alpha * acc[t][u][r] + bc;
                    float v = x2 / (1.f + expf(-x2));
                    rowsum[t][r] += v * w3c;
                }
        }
        #pragma unroll
        for (int t = 0; t < 4; ++t)
            #pragma unroll
            for (int r = 0; r < 4; ++r) {
                float s2 = rowsum[t][r];
                s2 += __shfl_xor(s2, 1, 64);
                s2 += __shfl_xor(s2, 2, 64);
                s2 += __shfl_xor(s2, 4, 64);
                s2 += __shfl_xor(s2, 8, 64);
                rowsum[t][r] = s2;
            }
        if (l16 == 0) {
            #pragma unroll
            for (int t = 0; t < 4; ++t) {
                int row0 = rowBase + wm * 64 + t * 16 + quad * 4;
                #pragma unroll
                for (int r = 0; r < 4; ++r)
                    if (row0 + r < M) atomicAdd(&outacc[row0 + r], rowsum[t][r]);
            }
        }
    }
}

__global__ void finalize_kernel(float* __restrict__ out, const int* __restrict__ Z,
                                const float* __restrict__ b3, int natoms)
{
    int a = blockIdx.x * 256 + threadIdx.x;
    if (a >= natoms) return;
    float v = out[a] + 0.1f * b3[0];
    out[a] = (Z[a] > 0) ? v : 0.f;
}

static inline size_t align_up(size_t x, size_t a) { return (x + a - 1) & ~(a - 1); }

extern "C" void kernel_launch(void* const* d_in, const int* in_sizes, int n_in,
                              void* d_out, int out_size, void* d_ws, size_t ws_size,
                              hipStream_t stream)
{
    const float* R       = (const float*)d_in[0];
    const int*   Z       = (const int*)  d_in[1];
    const int*   nbr     = (const int*)  d_in[2];
    const float* offsets = (const float*)d_in[4];
    const float* emb     = (const float*)d_in[5];
    const float* W1      = (const float*)d_in[6];
    const float* b1      = (const float*)d_in[7];
    const float* W2      = (const float*)d_in[8];
    const float* b2      = (const float*)d_in[9];
    const float* W3      = (const float*)d_in[10];
    const float* b3      = (const float*)d_in[11];

    int natoms = in_sizes[0] / 3;
    int npairs = in_sizes[2] / 2;
    int Mpad = ((natoms + 127) / 128) * 128;

    char* ws = (char*)d_ws;
    size_t off = 0;
    int* counts = (int*)(ws + off); off = align_up(off + natoms*4, 256);
    int* offs   = (int*)(ws + off); off = align_up(off + natoms*4, 256);
    int* cursor = (int*)(ws + off); off = align_up(off + natoms*4, 256);
    float* pairdata = (float*)(ws + off); off = align_up(off + (size_t)npairs*8*4, 256);
    __hip_bfloat16* W1t   = (__hip_bfloat16*)(ws + off); off = align_up(off + (size_t)UNITS*KP1*2, 256);
    __hip_bfloat16* W2t   = (__hip_bfloat16*)(ws + off); off = align_up(off + (size_t)UNITS*UNITS*2, 256);
    __hip_bfloat16* feats = (__hip_bfloat16*)(ws + off); off = align_up(off + (size_t)Mpad*KP1*2, 256);
    __hip_bfloat16* h1    = (__hip_bfloat16*)(ws + off); off = align_up(off + (size_t)Mpad*UNITS*2, 256);

    hipMemsetAsync(counts, 0, (size_t)natoms * sizeof(int), stream);
    hipMemsetAsync(d_out, 0, (size_t)natoms * sizeof(float), stream);

    int pgrid = (npairs + 255) / 256;
    hist_kernel<<<dim3(pgrid), 256, 0, stream>>>(R, nbr, offsets, counts, npairs);
    scan_kernel<<<dim3(1), 1024, 0, stream>>>(counts, offs, cursor, natoms);

    prep_w_t<<<dim3((UNITS*KP1 + 255)/256), 256, 0, stream>>>(W1, W1t, NFEAT, UNITS, KP1);
    prep_w_t<<<dim3((UNITS*UNITS + 255)/256), 256, 0, stream>>>(W2, W2t, UNITS, UNITS, UNITS);

    scatter_pair_kernel<<<dim3(pgrid), 256, 0, stream>>>(
        R, Z, nbr, offsets, emb, cursor, pairdata, npairs);

    moment_feat_kernel<<<dim3((natoms + 3) / 4), 256, 0, stream>>>(
        pairdata, offs, counts, feats, natoms);

    float a1 = 1.0f / sqrtf((float)NFEAT);
    float a2 = 1.0f / sqrtf((float)UNITS);
    dim3 ggrid(Mpad / 128, UNITS / 64);
    gemm_mfma_swish<<<ggrid, 256, 0, stream>>>(
        feats, W1t, b1, h1, nullptr, nullptr, KP1, natoms, a1, 0.f, 0);
    gemm_mfma_swish<<<ggrid, 256, 0, stream>>>(
        h1, W2t, b2, nullptr, W3, (float*)d_out, UNITS, natoms, a2, a2, 1);

    finalize_kernel<<<dim3((natoms + 255) / 256), 256, 0, stream>>>(
        (float*)d_out, Z, b3, natoms);
}

// Round 9
// 337.835 us; speedup vs baseline: 1.1166x; 1.1166x over previous
//
#include <hip/hip_runtime.h>
#include <hip/hip_bf16.h>
#include <cmath>

#define NSP 119
#define UNITS 512
#define NFEAT 360
#define KP1 384          // NFEAT padded to multiple of 32

typedef __attribute__((ext_vector_type(8))) short short8;
typedef __attribute__((ext_vector_type(4))) float floatx4;

// ---------- constant index tables ----------
__constant__ int T2I[15] = {0,1,1,2,2,2,3,3,3,3,4,4,4,4,4};
__constant__ int T2J[15] = {0,0,1,0,1,2,0,1,2,3,0,1,2,3,4};
__constant__ int T3A[35] = {0, 1,1,1, 2,2,2,2,2,2, 3,3,3,3,3,3,3,3,3,3, 4,4,4,4,4,4,4,4,4,4,4,4,4,4,4};
__constant__ int T3B[35] = {0, 0,1,1, 0,1,1,2,2,2, 0,1,1,2,2,2,3,3,3,3, 0,1,1,2,2,2,3,3,3,3,4,4,4,4,4};
__constant__ int T3C[35] = {0, 0,0,1, 0,0,1,0,1,2, 0,0,1,0,1,2,0,1,2,3, 0,0,1,0,1,2,0,1,2,3,0,1,2,3,4};
__constant__ int P2X[6] = {0,1,1,2,2,2};
__constant__ int P2Y[6] = {0,0,1,0,1,2};
__constant__ int P3X[10] = {0,1,1,1,2,2,2,2,2,2};
__constant__ int P3Y[10] = {0,0,1,1,0,1,1,2,2,2};
__constant__ int P3Z[10] = {0,0,0,1,0,0,1,0,1,2};

// ---------- phase 1a: histogram of in-cutoff pairs per center atom ----------
__global__ __launch_bounds__(256) void hist_kernel(
    const float* __restrict__ R, const int* __restrict__ nbr,
    const float* __restrict__ offsets, int* __restrict__ counts, int npairs)
{
    int p = blockIdx.x * 256 + threadIdx.x;
    if (p >= npairs) return;
    int i = nbr[p];
    int j = nbr[npairs + p];
    float dx = R[3*j]   - R[3*i]   + offsets[3*p];
    float dy = R[3*j+1] - R[3*i+1] + offsets[3*p+1];
    float dz = R[3*j+2] - R[3*i+2] + offsets[3*p+2];
    float dr2 = dx*dx + dy*dy + dz*dz;
    if (dr2 < 36.0f) atomicAdd(&counts[i], 1);
}

// ---------- phase 1b: exclusive scan, single block, 32 items/thread ----------
__global__ __launch_bounds__(1024) void scan_kernel(
    const int* __restrict__ counts, int* __restrict__ offs,
    int* __restrict__ cursor, int n)
{
    int tid = threadIdx.x;
    int lane = tid & 63, wid = tid >> 6;
    int beg = tid * 32;
    int local[32];
    int s = 0;
    #pragma unroll
    for (int k = 0; k < 32; ++k) {
        int idx = beg + k;
        int v = (idx < n) ? counts[idx] : 0;
        local[k] = s;
        s += v;
    }
    int incl = s;
    #pragma unroll
    for (int off = 1; off < 64; off <<= 1) {
        int t = __shfl_up(incl, off, 64);
        if (lane >= off) incl += t;
    }
    __shared__ int wsum[16];
    if (lane == 63) wsum[wid] = incl;
    __syncthreads();
    if (tid < 16) {
        int v = wsum[tid];
        int inc2 = v;
        #pragma unroll
        for (int off = 1; off < 16; off <<= 1) {
            int t = __shfl_up(inc2, off, 64);
            if (tid >= off) inc2 += t;
        }
        wsum[tid] = inc2 - v;
    }
    __syncthreads();
    int base = wsum[wid] + (incl - s);
    #pragma unroll
    for (int k = 0; k < 32; ++k) {
        int idx = beg + k;
        if (idx < n) { int v = base + local[k]; offs[idx] = v; cursor[idx] = v; }
    }
}

// ---------- phase 1c (merged): scatter + per-pair rad[5]+dn[3] record ----------
__global__ __launch_bounds__(256) void scatter_pair_kernel(
    const float* __restrict__ R, const int* __restrict__ Z,
    const int* __restrict__ nbr, const float* __restrict__ offsets,
    const float* __restrict__ emb, int* __restrict__ cursor,
    float* __restrict__ pairdata, int npairs)
{
    int p = blockIdx.x * 256 + threadIdx.x;
    if (p >= npairs) return;
    int i = nbr[p], j = nbr[npairs + p];
    float dx = R[3*j]   - R[3*i]   + offsets[3*p];
    float dy = R[3*j+1] - R[3*i+1] + offsets[3*p+1];
    float dz = R[3*j+2] - R[3*i+2] + offsets[3*p+2];
    float dr2 = dx*dx + dy*dy + dz*dz;
    if (!(dr2 < 36.0f)) return;
    int pos = atomicAdd(&cursor[i], 1);

    float dr = sqrtf(dr2);
    float inv = 1.0f / (dr + 1e-5f);
    float cutoff = 0.5f * (cosf(0.523598775598299f * dr) + 1.0f); // pi/R_MAX
    const float betta = 49.0f / 36.0f;
    const float rad_norm = expf(0.75f * logf(2.0f * betta / 3.14159265358979f));
    float basis[7];
    #pragma unroll
    for (int b = 0; b < 7; ++b) {
        float sh = 0.5f + b * (5.5f / 6.0f);
        float d = dr - sh;
        basis[b] = rad_norm * expf(-betta * d * d);
    }
    const float* e = emb + ((size_t)Z[j] * NSP + Z[i]) * 35;
    const float EMBN = 0.377964473009227f; // 1/sqrt(7)
    float rec[8];
    #pragma unroll
    for (int r = 0; r < 5; ++r) {
        float s = 0.f;
        #pragma unroll
        for (int b = 0; b < 7; ++b) s += e[r*7 + b] * basis[b];
        rec[r] = EMBN * s * cutoff;
    }
    rec[5] = dx * inv; rec[6] = dy * inv; rec[7] = dz * inv;
    float4* out = (float4*)(pairdata + (size_t)pos * 8);
    out[0] = make_float4(rec[0], rec[1], rec[2], rec[3]);
    out[1] = make_float4(rec[4], rec[5], rec[6], rec[7]);
}

// ---------- phase 2: one wave per atom: moments + contractions -> 360 bf16 feats ----------
#define SREC 12   // stage record stride (floats); [0..4]=rad, [5..7]=dn, [8]=1.0
__global__ __launch_bounds__(256) void moment_feat_kernel(
    const float* __restrict__ pairdata, const int* __restrict__ offs,
    const int* __restrict__ counts, __hip_bfloat16* __restrict__ feats, int natoms)
{
    int wv = threadIdx.x >> 6, lane = threadIdx.x & 63;
    int a = blockIdx.x * 4 + wv;
    __shared__ float stage[4][64][SREC];
    __shared__ float F[4][200];
    __shared__ float B2[4][135];
    __shared__ float A3[4][75];
    if (a >= natoms) return;   // wave-uniform; no __syncthreads in this kernel

    int start = offs[a], cnt = counts[a];

    int cr0, f00 = 8, f01 = 8, f02 = 8;
    if (lane < 5)       { cr0 = lane; }
    else if (lane < 20) { int c = lane - 5;  cr0 = c / 3; f00 = 5 + c % 3; }
    else if (lane < 50) { int c = lane - 20; cr0 = c / 6; int k = c % 6;
                          f00 = 5 + P2X[k]; f01 = 5 + P2Y[k]; }
    else                { int c = lane - 50; cr0 = c / 10; int k = c % 10;
                          f00 = 5 + P3X[k]; f01 = 5 + P3Y[k]; f02 = 5 + P3Z[k]; }
    int cr1 = 8, f10 = 8, f11 = 8, f12 = 8;
    if (lane < 36) { int c = 14 + lane; cr1 = c / 10; int k = c % 10;
                     f10 = 5 + P3X[k]; f11 = 5 + P3Y[k]; f12 = 5 + P3Z[k]; }

    float acc0 = 0.f, acc1 = 0.f;
    for (int base = 0; base < cnt; base += 64) {
        int m = min(64, cnt - base);
        if (lane < m) {
            const float4* pd = (const float4*)(pairdata + (size_t)(start + base + lane) * 8);
            float4 u = pd[0], v = pd[1];
            float* st = stage[wv][lane];
            ((float4*)st)[0] = u;
            ((float4*)st)[1] = v;
            st[8] = 1.0f;
        }
        __builtin_amdgcn_wave_barrier();
        for (int q = 0; q < m; ++q) {
            const float* s = stage[wv][q];
            acc0 += s[cr0] * s[f00] * s[f01] * s[f02];
            acc1 += s[cr1] * s[f10] * s[f11] * s[f12];
        }
        __builtin_amdgcn_wave_barrier();
    }
    float* raw = &stage[wv][0][0];
    __builtin_amdgcn_wave_barrier();
    raw[lane] = acc0;
    if (lane < 36) raw[64 + lane] = acc1;
    __builtin_amdgcn_wave_barrier();

    #pragma unroll
    for (int it = 0; it < 4; ++it) {
        int idx = lane + it * 64;
        if (idx < 200) {
            float v;
            if (idx < 20) {
                v = raw[idx];
            } else if (idx < 65) {
                int rel = idx - 20, r = rel / 9, q = rel % 9, x = q / 3, y = q % 3;
                int hi = max(x, y), lo = min(x, y);
                v = raw[20 + r*6 + hi*(hi+1)/2 + lo];
            } else {
                int rel = idx - 65, r = rel / 27, q = rel % 27;
                int x = q / 9, y = (q / 3) % 3, z = q % 3;
                int A = max(x, max(y, z)), C = min(x, min(y, z)), B = x + y + z - A - C;
                v = raw[50 + r*10 + A*(A+1)*(A+2)/6 + B*(B+1)/2 + C];
            }
            F[wv][idx] = v;
        }
    }
    __builtin_amdgcn_wave_barrier();

    const float* M0 = F[wv];
    const float* M1 = F[wv] + 5;    // [r*3+x]
    const float* M2 = F[wv] + 20;   // [r*9+x*3+y]
    const float* M3 = F[wv] + 65;   // [r*27+x*9+y*3+z]

    #pragma unroll
    for (int it = 0; it < 4; ++it) {
        int idx = lane + it * 64;
        if (idx < 135) {
            int p = idx / 9, zw = idx % 9, z = zw / 3, w_ = zw % 3;
            int r = T2I[p], s = T2J[p];
            float b = 0.f;
            for (int x = 0; x < 3; ++x)
                for (int y = 0; y < 3; ++y)
                    b += M3[r*27 + x*9 + y*3 + z] * M3[s*27 + x*9 + y*3 + w_];
            B2[wv][idx] = b;
        } else if (idx < 210) {
            int e = idx - 135;
            int rs = e / 3, z = e % 3;
            int r = rs / 5, s = rs % 5;
            float av = 0.f;
            for (int x = 0; x < 3; ++x)
                for (int y = 0; y < 3; ++y)
                    av += M3[r*27 + x*9 + y*3 + z] * M2[s*9 + x*3 + y];
            A3[wv][e] = av;
        }
    }
    __builtin_amdgcn_wave_barrier();

    __hip_bfloat16* out = feats + (size_t)a * KP1;
    for (int f = lane; f < NFEAT; f += 64) {
        float v = 0.f;
        if (f < 5) {
            v = M0[f];
        } else if (f < 20) {                 // c1
            int p = f - 5, r = T2I[p], s = T2J[p];
            for (int x = 0; x < 3; ++x) v += M1[r*3+x] * M1[s*3+x];
        } else if (f < 35) {                 // c2
            int p = f - 20, r = T2I[p], s = T2J[p];
            for (int q = 0; q < 9; ++q) v += M2[r*9+q] * M2[s*9+q];
        } else if (f < 50) {                 // c3
            int p = f - 35, r = T2I[p], s = T2J[p];
            for (int q = 0; q < 27; ++q) v += M3[r*27+q] * M3[s*27+q];
        } else if (f < 85) {                 // c4
            int q = f - 50, r = T3A[q], s = T3B[q], t = T3C[q];
            for (int x = 0; x < 3; ++x)
                for (int y = 0; y < 3; ++y)
                    for (int z = 0; z < 3; ++z)
                        v += M2[r*9+x*3+y] * M2[s*9+x*3+z] * M2[t*9+y*3+z];
        } else if (f < 160) {                // c5
            int q = f - 85, p = q / 5, t = q % 5, r = T2I[p], s = T2J[p];
            for (int x = 0; x < 3; ++x)
                for (int y = 0; y < 3; ++y)
                    v += M1[r*3+x] * M1[s*3+y] * M2[t*9+x*3+y];
        } else if (f < 235) {                // c6 via B2
            int q = f - 160, p = q / 5, t = q % 5;
            for (int zw = 0; zw < 9; ++zw)
                v += B2[wv][p*9 + zw] * M2[t*9 + zw];
        } else {                             // c7 via A3
            int q = f - 235, r = q / 25, s = (q / 5) % 5, t = q % 5;
            for (int z = 0; z < 3; ++z)
                v += A3[wv][(r*5+s)*3 + z] * M1[t*3 + z];
        }
        out[f] = __float2bfloat16(v);
    }
}

// ---------- weight transpose+pad to bf16: Wt[n*Kp+k] = W[k*N+n] ----------
__global__ __launch_bounds__(256) void prep_w_t(
    const float* __restrict__ W, __hip_bfloat16* __restrict__ Wt,
    int K, int N, int Kp)
{
    int idx = blockIdx.x * 256 + threadIdx.x;
    if (idx >= N * Kp) return;
    int n = idx / Kp, k = idx % Kp;
    float v = (k < K) ? W[(size_t)k * N + n] : 0.f;
    Wt[idx] = __float2bfloat16(v);
}

// ---------- bf16 MFMA GEMM, 128x128 tile, BK=32, reg-staged double-buffer ----------
// 4 col-tiles (vs 8 with 128x64): halves the structural worst-case A re-fetch
// (the R6-R8 counter pathology: FETCH up to 8x A + WRITE 10x C from L2 thrash).
// 2D grid; XCD 1D swizzle is banned (R6/R7: 40x WRITE amplification).
// LDS swizzle: chunk (row r, c) at pos r*4 + (c ^ ((r>>1)&3)) -> conflict-free.
// One __syncthreads per K-iter (double LDS buffer); 2-deep register prefetch.
__global__ __launch_bounds__(256) void gemm_mfma_swish(
    const __hip_bfloat16* __restrict__ A, const __hip_bfloat16* __restrict__ Bt,
    const float* __restrict__ bias, __hip_bfloat16* __restrict__ C,
    const float* __restrict__ w3, float* __restrict__ outacc,
    int Kp, int M, float alpha, float a3, int fuse)
{
    __shared__ float4 As[2][512];   // 128 rows x 4 chunks
    __shared__ float4 Bs[2][512];   // 128 rows x 4 chunks
    int tid = threadIdx.x;
    int wave = tid >> 6, lane = tid & 63;
    int quad = lane >> 4, l16 = lane & 15;
    int wm = wave >> 1, wn = wave & 1;   // 2x2 waves: 64-row x 64-col each
    int rowBase = blockIdx.x * 128;
    int colBase = blockIdx.y * 128;

    floatx4 acc[4][4] = {};

    // staging decode: thread -> (row, chunk); rows 0..63 and 64..127
    int r0 = tid >> 2, cA = tid & 3;
    int r1 = r0 + 64;
    int p0 = r0 * 4 + (cA ^ ((r0 >> 1) & 3));
    int p1 = r1 * 4 + (cA ^ ((r1 >> 1) & 3));

    const char* pa0 = (const char*)(A  + (size_t)(rowBase + r0) * Kp + cA * 8);
    const char* pa1 = (const char*)(A  + (size_t)(rowBase + r1) * Kp + cA * 8);
    const char* pb0 = (const char*)(Bt + (size_t)(colBase + r0) * Kp + cA * 8);
    const char* pb1 = (const char*)(Bt + (size_t)(colBase + r1) * Kp + cA * 8);

    // fragment read positions
    int posA[4], posB[4];
    #pragma unroll
    for (int t = 0; t < 4; ++t) {
        int rr = wm * 64 + t * 16 + l16;
        posA[t] = rr * 4 + (quad ^ ((rr >> 1) & 3));
        int cc = wn * 64 + t * 16 + l16;
        posB[t] = cc * 4 + (quad ^ ((cc >> 1) & 3));
    }

    int nK = Kp >> 5;
    // 2-deep prefetch: slot kt&1 holds data for iteration kt
    float4 ra0[2], ra1[2], rb0[2], rb1[2];
    ra0[0] = *(const float4*)pa0;
    ra1[0] = *(const float4*)pa1;
    rb0[0] = *(const float4*)pb0;
    rb1[0] = *(const float4*)pb1;
    ra0[1] = *(const float4*)(pa0 + 64);
    ra1[1] = *(const float4*)(pa1 + 64);
    rb0[1] = *(const float4*)(pb0 + 64);
    rb1[1] = *(const float4*)(pb1 + 64);

    for (int kt = 0; kt < nK; ++kt) {
        int sl = kt & 1;
        As[sl][p0] = ra0[sl];
        As[sl][p1] = ra1[sl];
        Bs[sl][p0] = rb0[sl];
        Bs[sl][p1] = rb1[sl];
        __syncthreads();
        if (kt + 2 < nK) {
            int off = (kt + 2) << 6;   // 32 bf16 = 64 bytes
            ra0[sl] = *(const float4*)(pa0 + off);
            ra1[sl] = *(const float4*)(pa1 + off);
            rb0[sl] = *(const float4*)(pb0 + off);
            rb1[sl] = *(const float4*)(pb1 + off);
        }
        short8 af[4], bf[4];
        #pragma unroll
        for (int t = 0; t < 4; ++t) af[t] = *(const short8*)(As[sl] + posA[t]);
        #pragma unroll
        for (int u = 0; u < 4; ++u) bf[u] = *(const short8*)(Bs[sl] + posB[u]);
        #pragma unroll
        for (int t = 0; t < 4; ++t)
            #pragma unroll
            for (int u = 0; u < 4; ++u)
                acc[t][u] = __builtin_amdgcn_mfma_f32_16x16x32_bf16(
                    af[t], bf[u], acc[t][u], 0, 0, 0);
        // next iter writes the other LDS buffer, whose readers all passed
        // this iter's barrier already -> no trailing barrier needed.
    }

    if (!fuse) {
        #pragma unroll
        for (int u = 0; u < 4; ++u) {
            int col = colBase + wn * 64 + u * 16 + l16;
            float bc = 0.1f * bias[col];
            #pragma unroll
            for (int t = 0; t < 4; ++t) {
                int row0 = rowBase + wm * 64 + t * 16 + quad * 4;
                #pragma unroll
                for (int r = 0; r < 4; ++r) {
                    float x2 = alpha * acc[t][u][r] + bc;
                    float v = x2 / (1.f + expf(-x2));
                    C[(size_t)(row0 + r) * UNITS + col] = __float2bfloat16(v);
                }
            }
        }
    } else {
        float rowsum[4][4] = {};
        #pragma unroll
        for (int u = 0; u < 4; ++u) {
            int col = colBase + wn * 64 + u * 16 + l16;
            float bc = 0.1f * bias[col];
            float w3c = w3[col] * a3;
            #pragma unroll
            for (int t = 0; t < 4; ++t)
                #pragma unroll
                for (int r = 0; r < 4; ++r) {
                    float x2 = alpha * acc[t][u][r] + bc;
                    float v = x2 / (1.f + expf(-x2));
                    rowsum[t][r] += v * w3c;
                }
        }
        #pragma unroll
        for (int t = 0; t < 4; ++t)
            #pragma unroll
            for (int r = 0; r < 4; ++r) {
                float s2 = rowsum[t][r];
                s2 += __shfl_xor(s2, 1, 64);
                s2 += __shfl_xor(s2, 2, 64);
                s2 += __shfl_xor(s2, 4, 64);
                s2 += __shfl_xor(s2, 8, 64);
                rowsum[t][r] = s2;
            }
        if (l16 == 0) {
            #pragma unroll
            for (int t = 0; t < 4; ++t) {
                int row0 = rowBase + wm * 64 + t * 16 + quad * 4;
                #pragma unroll
                for (int r = 0; r < 4; ++r)
                    if (row0 + r < M) atomicAdd(&outacc[row0 + r], rowsum[t][r]);
            }
        }
    }
}

__global__ void finalize_kernel(float* __restrict__ out, const int* __restrict__ Z,
                                const float* __restrict__ b3, int natoms)
{
    int a = blockIdx.x * 256 + threadIdx.x;
    if (a >= natoms) return;
    float v = out[a] + 0.1f * b3[0];
    out[a] = (Z[a] > 0) ? v : 0.f;
}

static inline size_t align_up(size_t x, size_t a) { return (x + a - 1) & ~(a - 1); }

extern "C" void kernel_launch(void* const* d_in, const int* in_sizes, int n_in,
                              void* d_out, int out_size, void* d_ws, size_t ws_size,
                              hipStream_t stream)
{
    const float* R       = (const float*)d_in[0];
    const int*   Z       = (const int*)  d_in[1];
    const int*   nbr     = (const int*)  d_in[2];
    const float* offsets = (const float*)d_in[4];
    const float* emb     = (const float*)d_in[5];
    const float* W1      = (const float*)d_in[6];
    const float* b1      = (const float*)d_in[7];
    const float* W2      = (const float*)d_in[8];
    const float* b2      = (const float*)d_in[9];
    const float* W3      = (const float*)d_in[10];
    const float* b3      = (const float*)d_in[11];

    int natoms = in_sizes[0] / 3;
    int npairs = in_sizes[2] / 2;
    int Mpad = ((natoms + 127) / 128) * 128;

    char* ws = (char*)d_ws;
    size_t off = 0;
    int* counts = (int*)(ws + off); off = align_up(off + natoms*4, 256);
    int* offs   = (int*)(ws + off); off = align_up(off + natoms*4, 256);
    int* cursor = (int*)(ws + off); off = align_up(off + natoms*4, 256);
    float* pairdata = (float*)(ws + off); off = align_up(off + (size_t)npairs*8*4, 256);
    __hip_bfloat16* W1t   = (__hip_bfloat16*)(ws + off); off = align_up(off + (size_t)UNITS*KP1*2, 256);
    __hip_bfloat16* W2t   = (__hip_bfloat16*)(ws + off); off = align_up(off + (size_t)UNITS*UNITS*2, 256);
    __hip_bfloat16* feats = (__hip_bfloat16*)(ws + off); off = align_up(off + (size_t)Mpad*KP1*2, 256);
    __hip_bfloat16* h1    = (__hip_bfloat16*)(ws + off); off = align_up(off + (size_t)Mpad*UNITS*2, 256);

    hipMemsetAsync(counts, 0, (size_t)natoms * sizeof(int), stream);
    hipMemsetAsync(d_out, 0, (size_t)natoms * sizeof(float), stream);

    int pgrid = (npairs + 255) / 256;
    hist_kernel<<<dim3(pgrid), 256, 0, stream>>>(R, nbr, offsets, counts, npairs);
    scan_kernel<<<dim3(1), 1024, 0, stream>>>(counts, offs, cursor, natoms);

    prep_w_t<<<dim3((UNITS*KP1 + 255)/256), 256, 0, stream>>>(W1, W1t, NFEAT, UNITS, KP1);
    prep_w_t<<<dim3((UNITS*UNITS + 255)/256), 256, 0, stream>>>(W2, W2t, UNITS, UNITS, UNITS);

    scatter_pair_kernel<<<dim3(pgrid), 256, 0, stream>>>(
        R, Z, nbr, offsets, emb, cursor, pairdata, npairs);

    moment_feat_kernel<<<dim3((natoms + 3) / 4), 256, 0, stream>>>(
        pairdata, offs, counts, feats, natoms);

    float a1 = 1.0f / sqrtf((float)NFEAT);
    float a2 = 1.0f / sqrtf((float)UNITS);
    dim3 ggrid(Mpad / 128, UNITS / 128);
    gemm_mfma_swish<<<ggrid, 256, 0, stream>>>(
        feats, W1t, b1, h1, nullptr, nullptr, KP1, natoms, a1, 0.f, 0);
    gemm_mfma_swish<<<ggrid, 256, 0, stream>>>(
        h1, W2t, b2, nullptr, W3, (float*)d_out, UNITS, natoms, a2, a2, 1);

    finalize_kernel<<<dim3((natoms + 255) / 256), 256, 0, stream>>>(
        (float*)d_out, Z, b3, natoms);
}

// Round 10
// 329.282 us; speedup vs baseline: 1.1456x; 1.0260x over previous
//
#include <hip/hip_runtime.h>
#include <hip/hip_bf16.h>
#include <cmath>

#define NSP 119
#define UNITS 512
#define NFEAT 360
#define KP1 384          // NFEAT padded to multiple of 32

typedef __attribute__((ext_vector_type(8))) short short8;
typedef __attribute__((ext_vector_type(4))) float floatx4;

// ---------- constant index tables ----------
__constant__ int T2I[15] = {0,1,1,2,2,2,3,3,3,3,4,4,4,4,4};
__constant__ int T2J[15] = {0,0,1,0,1,2,0,1,2,3,0,1,2,3,4};
__constant__ int T3A[35] = {0, 1,1,1, 2,2,2,2,2,2, 3,3,3,3,3,3,3,3,3,3, 4,4,4,4,4,4,4,4,4,4,4,4,4,4,4};
__constant__ int T3B[35] = {0, 0,1,1, 0,1,1,2,2,2, 0,1,1,2,2,2,3,3,3,3, 0,1,1,2,2,2,3,3,3,3,4,4,4,4,4};
__constant__ int T3C[35] = {0, 0,0,1, 0,0,1,0,1,2, 0,0,1,0,1,2,0,1,2,3, 0,0,1,0,1,2,0,1,2,3,0,1,2,3,4};
__constant__ int P2X[6] = {0,1,1,2,2,2};
__constant__ int P2Y[6] = {0,0,1,0,1,2};
__constant__ int P3X[10] = {0,1,1,1,2,2,2,2,2,2};
__constant__ int P3Y[10] = {0,0,1,1,0,1,1,2,2,2};
__constant__ int P3Z[10] = {0,0,0,1,0,0,1,0,1,2};

// ---------- phase 1a: histogram of in-cutoff pairs per center atom ----------
__global__ __launch_bounds__(256) void hist_kernel(
    const float* __restrict__ R, const int* __restrict__ nbr,
    const float* __restrict__ offsets, int* __restrict__ counts, int npairs)
{
    int p = blockIdx.x * 256 + threadIdx.x;
    if (p >= npairs) return;
    int i = nbr[p];
    int j = nbr[npairs + p];
    float dx = R[3*j]   - R[3*i]   + offsets[3*p];
    float dy = R[3*j+1] - R[3*i+1] + offsets[3*p+1];
    float dz = R[3*j+2] - R[3*i+2] + offsets[3*p+2];
    float dr2 = dx*dx + dy*dy + dz*dz;
    if (dr2 < 36.0f) atomicAdd(&counts[i], 1);
}

// ---------- phase 1b: exclusive scan, single block, 32 items/thread ----------
__global__ __launch_bounds__(1024) void scan_kernel(
    const int* __restrict__ counts, int* __restrict__ offs,
    int* __restrict__ cursor, int n)
{
    int tid = threadIdx.x;
    int lane = tid & 63, wid = tid >> 6;
    int beg = tid * 32;
    int local[32];
    int s = 0;
    #pragma unroll
    for (int k = 0; k < 32; ++k) {
        int idx = beg + k;
        int v = (idx < n) ? counts[idx] : 0;
        local[k] = s;
        s += v;
    }
    int incl = s;
    #pragma unroll
    for (int off = 1; off < 64; off <<= 1) {
        int t = __shfl_up(incl, off, 64);
        if (lane >= off) incl += t;
    }
    __shared__ int wsum[16];
    if (lane == 63) wsum[wid] = incl;
    __syncthreads();
    if (tid < 16) {
        int v = wsum[tid];
        int inc2 = v;
        #pragma unroll
        for (int off = 1; off < 16; off <<= 1) {
            int t = __shfl_up(inc2, off, 64);
            if (tid >= off) inc2 += t;
        }
        wsum[tid] = inc2 - v;
    }
    __syncthreads();
    int base = wsum[wid] + (incl - s);
    #pragma unroll
    for (int k = 0; k < 32; ++k) {
        int idx = beg + k;
        if (idx < n) { int v = base + local[k]; offs[idx] = v; cursor[idx] = v; }
    }
}

// ---------- phase 1c (merged): scatter + per-pair rad[5]+dn[3] record ----------
__global__ __launch_bounds__(256) void scatter_pair_kernel(
    const float* __restrict__ R, const int* __restrict__ Z,
    const int* __restrict__ nbr, const float* __restrict__ offsets,
    const float* __restrict__ emb, int* __restrict__ cursor,
    float* __restrict__ pairdata, int npairs)
{
    int p = blockIdx.x * 256 + threadIdx.x;
    if (p >= npairs) return;
    int i = nbr[p], j = nbr[npairs + p];
    float dx = R[3*j]   - R[3*i]   + offsets[3*p];
    float dy = R[3*j+1] - R[3*i+1] + offsets[3*p+1];
    float dz = R[3*j+2] - R[3*i+2] + offsets[3*p+2];
    float dr2 = dx*dx + dy*dy + dz*dz;
    if (!(dr2 < 36.0f)) return;
    int pos = atomicAdd(&cursor[i], 1);

    float dr = sqrtf(dr2);
    float inv = 1.0f / (dr + 1e-5f);
    float cutoff = 0.5f * (cosf(0.523598775598299f * dr) + 1.0f); // pi/R_MAX
    const float betta = 49.0f / 36.0f;
    const float rad_norm = expf(0.75f * logf(2.0f * betta / 3.14159265358979f));
    float basis[7];
    #pragma unroll
    for (int b = 0; b < 7; ++b) {
        float sh = 0.5f + b * (5.5f / 6.0f);
        float d = dr - sh;
        basis[b] = rad_norm * expf(-betta * d * d);
    }
    const float* e = emb + ((size_t)Z[j] * NSP + Z[i]) * 35;
    const float EMBN = 0.377964473009227f; // 1/sqrt(7)
    float rec[8];
    #pragma unroll
    for (int r = 0; r < 5; ++r) {
        float s = 0.f;
        #pragma unroll
        for (int b = 0; b < 7; ++b) s += e[r*7 + b] * basis[b];
        rec[r] = EMBN * s * cutoff;
    }
    rec[5] = dx * inv; rec[6] = dy * inv; rec[7] = dz * inv;
    float4* out = (float4*)(pairdata + (size_t)pos * 8);
    out[0] = make_float4(rec[0], rec[1], rec[2], rec[3]);
    out[1] = make_float4(rec[4], rec[5], rec[6], rec[7]);
}

// ---------- phase 2: one wave per atom: moments + contractions -> 360 bf16 feats ----------
#define SREC 12   // stage record stride (floats); [0..4]=rad, [5..7]=dn, [8]=1.0
__global__ __launch_bounds__(256) void moment_feat_kernel(
    const float* __restrict__ pairdata, const int* __restrict__ offs,
    const int* __restrict__ counts, __hip_bfloat16* __restrict__ feats, int natoms)
{
    int wv = threadIdx.x >> 6, lane = threadIdx.x & 63;
    int a = blockIdx.x * 4 + wv;
    __shared__ float stage[4][64][SREC];
    __shared__ float F[4][200];
    __shared__ float B2[4][135];
    __shared__ float A3[4][75];
    if (a >= natoms) return;   // wave-uniform; no __syncthreads in this kernel

    int start = offs[a], cnt = counts[a];

    int cr0, f00 = 8, f01 = 8, f02 = 8;
    if (lane < 5)       { cr0 = lane; }
    else if (lane < 20) { int c = lane - 5;  cr0 = c / 3; f00 = 5 + c % 3; }
    else if (lane < 50) { int c = lane - 20; cr0 = c / 6; int k = c % 6;
                          f00 = 5 + P2X[k]; f01 = 5 + P2Y[k]; }
    else                { int c = lane - 50; cr0 = c / 10; int k = c % 10;
                          f00 = 5 + P3X[k]; f01 = 5 + P3Y[k]; f02 = 5 + P3Z[k]; }
    int cr1 = 8, f10 = 8, f11 = 8, f12 = 8;
    if (lane < 36) { int c = 14 + lane; cr1 = c / 10; int k = c % 10;
                     f10 = 5 + P3X[k]; f11 = 5 + P3Y[k]; f12 = 5 + P3Z[k]; }

    float acc0 = 0.f, acc1 = 0.f;
    for (int base = 0; base < cnt; base += 64) {
        int m = min(64, cnt - base);
        if (lane < m) {
            const float4* pd = (const float4*)(pairdata + (size_t)(start + base + lane) * 8);
            float4 u = pd[0], v = pd[1];
            float* st = stage[wv][lane];
            ((float4*)st)[0] = u;
            ((float4*)st)[1] = v;
            st[8] = 1.0f;
        }
        __builtin_amdgcn_wave_barrier();
        for (int q = 0; q < m; ++q) {
            const float* s = stage[wv][q];
            acc0 += s[cr0] * s[f00] * s[f01] * s[f02];
            acc1 += s[cr1] * s[f10] * s[f11] * s[f12];
        }
        __builtin_amdgcn_wave_barrier();
    }
    float* raw = &stage[wv][0][0];
    __builtin_amdgcn_wave_barrier();
    raw[lane] = acc0;
    if (lane < 36) raw[64 + lane] = acc1;
    __builtin_amdgcn_wave_barrier();

    #pragma unroll
    for (int it = 0; it < 4; ++it) {
        int idx = lane + it * 64;
        if (idx < 200) {
            float v;
            if (idx < 20) {
                v = raw[idx];
            } else if (idx < 65) {
                int rel = idx - 20, r = rel / 9, q = rel % 9, x = q / 3, y = q % 3;
                int hi = max(x, y), lo = min(x, y);
                v = raw[20 + r*6 + hi*(hi+1)/2 + lo];
            } else {
                int rel = idx - 65, r = rel / 27, q = rel % 27;
                int x = q / 9, y = (q / 3) % 3, z = q % 3;
                int A = max(x, max(y, z)), C = min(x, min(y, z)), B = x + y + z - A - C;
                v = raw[50 + r*10 + A*(A+1)*(A+2)/6 + B*(B+1)/2 + C];
            }
            F[wv][idx] = v;
        }
    }
    __builtin_amdgcn_wave_barrier();

    const float* M0 = F[wv];
    const float* M1 = F[wv] + 5;    // [r*3+x]
    const float* M2 = F[wv] + 20;   // [r*9+x*3+y]
    const float* M3 = F[wv] + 65;   // [r*27+x*9+y*3+z]

    #pragma unroll
    for (int it = 0; it < 4; ++it) {
        int idx = lane + it * 64;
        if (idx < 135) {
            int p = idx / 9, zw = idx % 9, z = zw / 3, w_ = zw % 3;
            int r = T2I[p], s = T2J[p];
            float b = 0.f;
            for (int x = 0; x < 3; ++x)
                for (int y = 0; y < 3; ++y)
                    b += M3[r*27 + x*9 + y*3 + z] * M3[s*27 + x*9 + y*3 + w_];
            B2[wv][idx] = b;
        } else if (idx < 210) {
            int e = idx - 135;
            int rs = e / 3, z = e % 3;
            int r = rs / 5, s = rs % 5;
            float av = 0.f;
            for (int x = 0; x < 3; ++x)
                for (int y = 0; y < 3; ++y)
                    av += M3[r*27 + x*9 + y*3 + z] * M2[s*9 + x*3 + y];
            A3[wv][e] = av;
        }
    }
    __builtin_amdgcn_wave_barrier();

    __hip_bfloat16* out = feats + (size_t)a * KP1;
    for (int f = lane; f < NFEAT; f += 64) {
        float v = 0.f;
        if (f < 5) {
            v = M0[f];
        } else if (f < 20) {                 // c1
            int p = f - 5, r = T2I[p], s = T2J[p];
            for (int x = 0; x < 3; ++x) v += M1[r*3+x] * M1[s*3+x];
        } else if (f < 35) {                 // c2
            int p = f - 20, r = T2I[p], s = T2J[p];
            for (int q = 0; q < 9; ++q) v += M2[r*9+q] * M2[s*9+q];
        } else if (f < 50) {                 // c3
            int p = f - 35, r = T2I[p], s = T2J[p];
            for (int q = 0; q < 27; ++q) v += M3[r*27+q] * M3[s*27+q];
        } else if (f < 85) {                 // c4
            int q = f - 50, r = T3A[q], s = T3B[q], t = T3C[q];
            for (int x = 0; x < 3; ++x)
                for (int y = 0; y < 3; ++y)
                    for (int z = 0; z < 3; ++z)
                        v += M2[r*9+x*3+y] * M2[s*9+x*3+z] * M2[t*9+y*3+z];
        } else if (f < 160) {                // c5
            int q = f - 85, p = q / 5, t = q % 5, r = T2I[p], s = T2J[p];
            for (int x = 0; x < 3; ++x)
                for (int y = 0; y < 3; ++y)
                    v += M1[r*3+x] * M1[s*3+y] * M2[t*9+x*3+y];
        } else if (f < 235) {                // c6 via B2
            int q = f - 160, p = q / 5, t = q % 5;
            for (int zw = 0; zw < 9; ++zw)
                v += B2[wv][p*9 + zw] * M2[t*9 + zw];
        } else {                             // c7 via A3
            int q = f - 235, r = q / 25, s = (q / 5) % 5, t = q % 5;
            for (int z = 0; z < 3; ++z)
                v += A3[wv][(r*5+s)*3 + z] * M1[t*3 + z];
        }
        out[f] = __float2bfloat16(v);
    }
}

// ---------- weight transpose+pad to bf16 (both layers in one launch) ----------
__global__ __launch_bounds__(256) void prep_w_both(
    const float* __restrict__ W1, __hip_bfloat16* __restrict__ W1t,
    const float* __restrict__ W2, __hip_bfloat16* __restrict__ W2t)
{
    int idx = blockIdx.x * 256 + threadIdx.x;
    const int n1 = UNITS * KP1;
    if (idx < n1) {
        int n = idx / KP1, k = idx % KP1;
        float v = (k < NFEAT) ? W1[(size_t)k * UNITS + n] : 0.f;
        W1t[idx] = __float2bfloat16(v);
    } else if (idx < n1 + UNITS * UNITS) {
        int e = idx - n1;
        int n = e / UNITS, k = e % UNITS;
        W2t[e] = __float2bfloat16(W2[(size_t)k * UNITS + n]);
    }
}

// ---------- bf16 MFMA GEMM, 128x128 tile, BK=32, 512 threads / 8 waves ----------
// 8 waves (2 row x 4 col, 64x32 each) double the resident waves per block vs
// R9's 4 — attacks the measured 15% occupancy (628 blocks, latency-bound).
// 2D grid; XCD 1D swizzle banned (R6/R7 pathology). LDS swizzle: chunk
// (row r, c) at pos r*4 + (c ^ ((r>>1)&3)) -> conflict-free. One barrier per
// K-iter (double LDS buffer); 2-deep register prefetch; staging = exactly one
// float4 per thread per buffer.
__global__ __launch_bounds__(512) void gemm_mfma_swish(
    const __hip_bfloat16* __restrict__ A, const __hip_bfloat16* __restrict__ Bt,
    const float* __restrict__ bias, __hip_bfloat16* __restrict__ C,
    const float* __restrict__ w3, float* __restrict__ outacc,
    int Kp, int M, float alpha, float a3, int fuse)
{
    __shared__ float4 As[2][512];   // 128 rows x 4 chunks
    __shared__ float4 Bs[2][512];   // 128 rows x 4 chunks
    int tid = threadIdx.x;
    int wave = tid >> 6, lane = tid & 63;
    int quad = lane >> 4, l16 = lane & 15;
    int wm = wave >> 2, wn = wave & 3;   // 2x4 waves: 64-row x 32-col each
    int rowBase = blockIdx.x * 128;
    int colBase = blockIdx.y * 128;

    floatx4 acc[4][2] = {};

    // staging decode: one (row, chunk) slot per thread
    int r0 = tid >> 2, cA = tid & 3;     // rows 0..127
    int p0 = r0 * 4 + (cA ^ ((r0 >> 1) & 3));

    const char* pa = (const char*)(A  + (size_t)(rowBase + r0) * Kp + cA * 8);
    const char* pb = (const char*)(Bt + (size_t)(colBase + r0) * Kp + cA * 8);

    // fragment read positions
    int posA[4], posB[2];
    #pragma unroll
    for (int t = 0; t < 4; ++t) {
        int rr = wm * 64 + t * 16 + l16;
        posA[t] = rr * 4 + (quad ^ ((rr >> 1) & 3));
    }
    #pragma unroll
    for (int u = 0; u < 2; ++u) {
        int cc = wn * 32 + u * 16 + l16;
        posB[u] = cc * 4 + (quad ^ ((cc >> 1) & 3));
    }

    int nK = Kp >> 5;
    // 2-deep prefetch: slot kt&1 holds data for iteration kt
    float4 ra[2], rb[2];
    ra[0] = *(const float4*)pa;
    rb[0] = *(const float4*)pb;
    ra[1] = *(const float4*)(pa + 64);
    rb[1] = *(const float4*)(pb + 64);

    for (int kt = 0; kt < nK; ++kt) {
        int sl = kt & 1;
        As[sl][p0] = ra[sl];
        Bs[sl][p0] = rb[sl];
        __syncthreads();
        if (kt + 2 < nK) {
            int off = (kt + 2) << 6;   // 32 bf16 = 64 bytes
            ra[sl] = *(const float4*)(pa + off);
            rb[sl] = *(const float4*)(pb + off);
        }
        short8 af[4], bf[2];
        #pragma unroll
        for (int t = 0; t < 4; ++t) af[t] = *(const short8*)(As[sl] + posA[t]);
        #pragma unroll
        for (int u = 0; u < 2; ++u) bf[u] = *(const short8*)(Bs[sl] + posB[u]);
        #pragma unroll
        for (int t = 0; t < 4; ++t)
            #pragma unroll
            for (int u = 0; u < 2; ++u)
                acc[t][u] = __builtin_amdgcn_mfma_f32_16x16x32_bf16(
                    af[t], bf[u], acc[t][u], 0, 0, 0);
        // next iter writes the other LDS buffer, whose readers all passed
        // this iter's barrier already -> no trailing barrier needed.
    }

    if (!fuse) {
        #pragma unroll
        for (int u = 0; u < 2; ++u) {
            int col = colBase + wn * 32 + u * 16 + l16;
            float bc = 0.1f * bias[col];
            #pragma unroll
            for (int t = 0; t < 4; ++t) {
                int row0 = rowBase + wm * 64 + t * 16 + quad * 4;
                #pragma unroll
                for (int r = 0; r < 4; ++r) {
                    float x2 = alpha * acc[t][u][r] + bc;
                    float v = x2 / (1.f + expf(-x2));
                    C[(size_t)(row0 + r) * UNITS + col] = __float2bfloat16(v);
                }
            }
        }
    } else {
        float rowsum[4][4] = {};
        #pragma unroll
        for (int u = 0; u < 2; ++u) {
            int col = colBase + wn * 32 + u * 16 + l16;
            float bc = 0.1f * bias[col];
            float w3c = w3[col] * a3;
            #pragma unroll
            for (int t = 0; t < 4; ++t)
                #pragma unroll
                for (int r = 0; r < 4; ++r) {
                    float x2 = alpha * acc[t][u][r] + bc;
                    float v = x2 / (1.f + expf(-x2));
                    rowsum[t][r] += v * w3c;
                }
        }
        #pragma unroll
        for (int t = 0; t < 4; ++t)
            #pragma unroll
            for (int r = 0; r < 4; ++r) {
                float s2 = rowsum[t][r];
                s2 += __shfl_xor(s2, 1, 64);
                s2 += __shfl_xor(s2, 2, 64);
                s2 += __shfl_xor(s2, 4, 64);
                s2 += __shfl_xor(s2, 8, 64);
                rowsum[t][r] = s2;
            }
        if (l16 == 0) {
            #pragma unroll
            for (int t = 0; t < 4; ++t) {
                int row0 = rowBase + wm * 64 + t * 16 + quad * 4;
                #pragma unroll
                for (int r = 0; r < 4; ++r)
                    if (row0 + r < M) atomicAdd(&outacc[row0 + r], rowsum[t][r]);
            }
        }
    }
}

__global__ void finalize_kernel(float* __restrict__ out, const int* __restrict__ Z,
                                const float* __restrict__ b3, int natoms)
{
    int a = blockIdx.x * 256 + threadIdx.x;
    if (a >= natoms) return;
    float v = out[a] + 0.1f * b3[0];
    out[a] = (Z[a] > 0) ? v : 0.f;
}

static inline size_t align_up(size_t x, size_t a) { return (x + a - 1) & ~(a - 1); }

extern "C" void kernel_launch(void* const* d_in, const int* in_sizes, int n_in,
                              void* d_out, int out_size, void* d_ws, size_t ws_size,
                              hipStream_t stream)
{
    const float* R       = (const float*)d_in[0];
    const int*   Z       = (const int*)  d_in[1];
    const int*   nbr     = (const int*)  d_in[2];
    const float* offsets = (const float*)d_in[4];
    const float* emb     = (const float*)d_in[5];
    const float* W1      = (const float*)d_in[6];
    const float* b1      = (const float*)d_in[7];
    const float* W2      = (const float*)d_in[8];
    const float* b2      = (const float*)d_in[9];
    const float* W3      = (const float*)d_in[10];
    const float* b3      = (const float*)d_in[11];

    int natoms = in_sizes[0] / 3;
    int npairs = in_sizes[2] / 2;
    int Mpad = ((natoms + 127) / 128) * 128;

    char* ws = (char*)d_ws;
    size_t off = 0;
    int* counts = (int*)(ws + off); off = align_up(off + natoms*4, 256);
    int* offs   = (int*)(ws + off); off = align_up(off + natoms*4, 256);
    int* cursor = (int*)(ws + off); off = align_up(off + natoms*4, 256);
    float* pairdata = (float*)(ws + off); off = align_up(off + (size_t)npairs*8*4, 256);
    __hip_bfloat16* W1t   = (__hip_bfloat16*)(ws + off); off = align_up(off + (size_t)UNITS*KP1*2, 256);
    __hip_bfloat16* W2t   = (__hip_bfloat16*)(ws + off); off = align_up(off + (size_t)UNITS*UNITS*2, 256);
    __hip_bfloat16* feats = (__hip_bfloat16*)(ws + off); off = align_up(off + (size_t)Mpad*KP1*2, 256);
    __hip_bfloat16* h1    = (__hip_bfloat16*)(ws + off); off = align_up(off + (size_t)Mpad*UNITS*2, 256);

    hipMemsetAsync(counts, 0, (size_t)natoms * sizeof(int), stream);
    hipMemsetAsync(d_out, 0, (size_t)natoms * sizeof(float), stream);

    int pgrid = (npairs + 255) / 256;
    hist_kernel<<<dim3(pgrid), 256, 0, stream>>>(R, nbr, offsets, counts, npairs);
    scan_kernel<<<dim3(1), 1024, 0, stream>>>(counts, offs, cursor, natoms);

    int wtot = UNITS * KP1 + UNITS * UNITS;
    prep_w_both<<<dim3((wtot + 255)/256), 256, 0, stream>>>(W1, W1t, W2, W2t);

    scatter_pair_kernel<<<dim3(pgrid), 256, 0, stream>>>(
        R, Z, nbr, offsets, emb, cursor, pairdata, npairs);

    moment_feat_kernel<<<dim3((natoms + 3) / 4), 256, 0, stream>>>(
        pairdata, offs, counts, feats, natoms);

    float a1 = 1.0f / sqrtf((float)NFEAT);
    float a2 = 1.0f / sqrtf((float)UNITS);
    dim3 ggrid(Mpad / 128, UNITS / 128);
    gemm_mfma_swish<<<ggrid, 512, 0, stream>>>(
        feats, W1t, b1, h1, nullptr, nullptr, KP1, natoms, a1, 0.f, 0);
    gemm_mfma_swish<<<ggrid, 512, 0, stream>>>(
        h1, W2t, b2, nullptr, W3, (float*)d_out, UNITS, natoms, a2, a2, 1);

    finalize_kernel<<<dim3((natoms + 255) / 256), 256, 0, stream>>>(
        (float*)d_out, Z, b3, natoms);
}